// Round 8
// baseline (520.522 us; speedup 1.0000x reference)
//
#include <hip/hip_runtime.h>

// Fast HW transcendentals (v_exp_f32 / v_log_f32 / v_rcp_f32), with fallbacks.
#if __has_builtin(__builtin_amdgcn_exp2f)
#define FAST_EXP2(x) __builtin_amdgcn_exp2f(x)
#else
#define FAST_EXP2(x) exp2f(x)
#endif
#if __has_builtin(__builtin_amdgcn_logf)
#define FAST_LOG2(x) __builtin_amdgcn_logf(x)
#else
#define FAST_LOG2(x) log2f(x)
#endif
#if __has_builtin(__builtin_amdgcn_rcpf)
#define FAST_RCP(x) __builtin_amdgcn_rcpf(x)
#else
#define FAST_RCP(x) (1.0f / (x))
#endif

#define LOG2E 1.44269504088896340736f

// Compiler-generated vector math ONLY (rounds 4-6 condemned inline-asm v_pk_*).
typedef float v2f __attribute__((ext_vector_type(2)));

__device__ __forceinline__ v2f v2fma(v2f a, v2f b, v2f c) {
    return __builtin_elementwise_fma(a, b, c);
}

// R13: persistent blocks + software-pipelined row loads.
// Ledger: R10 occupancy-cap neutral, R11 LDS-b128 neutral, R12 trans-22%
// neutral, R9 waves 8->3 = +50% time. The kernel is slot-time-bound: ~40%
// VALUBusy with ~1000 cyc of dead time per wave at BLOCK ENTRY (weight load +
// LDS staging + barrier + x/S1 load latency), paid once per 256 rows by every
// wave (7813 short-lived blocks). Fix: 2048 persistent blocks (8/CU) stage
// weights ONCE, grid-stride over ~4 chunks, and prefetch the next chunk's
// x/S1 BEFORE computing the current chunk (latency hidden under ~1300 cyc of
// compute). Compute body is verbatim R12 (absmax 1.22e-4 verified).

// tanh on a pair whose input is PRE-SCALED by 2*log2e: tanh = 1 - 2/(exp2(t)+1).
// One shared rcp for the pair.
__device__ __forceinline__ v2f fast_tanh2_scaled(v2f t) {
    v2f e;
    e.x = FAST_EXP2(t.x);
    e.y = FAST_EXP2(t.y);
    v2f d = e + (v2f)(1.0f);
    float rp = FAST_RCP(d.x * d.y);
    v2f r;
    r.x = d.y * rp;
    r.y = d.x * rp;
    return v2fma((v2f)(-2.0f), r, (v2f)(1.0f));
}

// sigmoid whose input is PRE-SCALED by -log2e: 1/(1+exp2(t)).
__device__ __forceinline__ float fast_sigmoid_scaled(float t) {
    return FAST_RCP(1.0f + FAST_EXP2(t));
}

constexpr int BLOCK = 256;

__global__ __launch_bounds__(256, 8) void subsurf_kernel(
    const float* __restrict__ x, const float* __restrict__ S1,
    const float* __restrict__ W1, const float* __restrict__ b1,
    const float* __restrict__ W2, const float* __restrict__ b2,
    const float* __restrict__ W3, const float* __restrict__ b3,
    float* __restrict__ out, int n)
{
    // LDS layout (R12's pre-scaled b128-bundled layout):
    //   A (L1): 9 groups x 12 floats @0:   [8x W1' pairs][2x b1'][2 pad] (48B)
    //   B (L2): 9 groups x 16 floats @108: [12x W2' pairs][2x b2'][2 pad] (64B)
    //   C (L3): 3 groups x  8 floats @252: [6x W3'][b3'][pad] (32B)
    __shared__ __align__(16) float w[280];
    int t = threadIdx.x;

    // First chunk for this block; issue row loads IMMEDIATELY so their
    // latency overlaps the weight staging below (clamped: always in-bounds).
    int c = blockIdx.x;
    int i = c * BLOCK + t;
    int ic = min(i, n - 1);
    float4 xv = ((const float4*)x)[ic];
    float s1v = S1[ic];

    const float SC_H = 2.0f * LOG2E;   // hidden-layer fold (tanh input scale)
    const float SC_O = -LOG2E;         // output-layer fold (sigmoid input scale)
    if (t < 252) {
        if (t < 108) {
            // A region: g=(k*3+jp), r in [0,12)
            int g = t / 12, r = t % 12;
            int k = g / 3, jp = g % 3;
            float v = 0.0f;
            if (r < 8)       v = SC_H * W1[k * 24 + (r >> 1) * 6 + 2 * jp + (r & 1)];
            else if (r < 10) v = SC_H * b1[k * 6 + 2 * jp + (r - 8)];
            w[t] = v;
        } else {
            // B region: u in [0,144), g=(k*3+jp), r in [0,16)
            int u = t - 108;
            int g = u / 16, r = u % 16;
            int k = g / 3, jp = g % 3;
            float v = 0.0f;
            if (r < 12)      v = SC_H * W2[k * 36 + (r >> 1) * 6 + 2 * jp + (r & 1)];
            else if (r < 14) v = SC_H * b2[k * 6 + 2 * jp + (r - 12)];
            w[t] = v;
        }
    }
    if (t < 24) {
        int k = t / 8, r = t % 8;
        float v = 0.0f;
        if (r < 6)       v = SC_O * W3[k * 6 + r];
        else if (r == 6) v = SC_O * b3[k];
        w[252 + t] = v;
    }
    __syncthreads();

    // Bit-match numpy f32 constant arithmetic for lows / (highs - lows).
    const float lows[3]   = {100.0f, 0.01f, 0.01f};
    const float ranges[3] = {500.0f - 100.0f, 100.0f - 0.01f, 10.0f - 0.01f};
    const int stride = gridDim.x;

    while (true) {
        // Prefetch next chunk's row data before the long compute; vmcnt-based
        // waits mean compute below does NOT wait on these loads.
        int cn = c + stride;
        bool has_next = cn * BLOCK < n;   // block-uniform branch
        float4 xv_n = xv;
        float s1_n = s1v;
        if (has_next) {
            int in_ = min(cn * BLOCK + t, n - 1);
            xv_n = ((const float4*)x)[in_];
            s1_n = S1[in_];
        }

        float xs[4] = {xv.x, xv.y, xv.z, xv.w};
        float s1 = s1v;

        float vals[3];
        #pragma unroll
        for (int k = 0; k < 3; ++k) {
            float h1[6];
            #pragma unroll
            for (int jp = 0; jp < 3; ++jp) {
                const float* ga = w + (k * 3 + jp) * 12;
                float4 wa = *(const float4*)(ga);      // W1' pairs d=0,1
                float4 wb = *(const float4*)(ga + 4);  // W1' pairs d=2,3
                v2f acc = *(const v2f*)(ga + 8);       // b1' pair
                acc = v2fma((v2f)(xs[0]), (v2f){wa.x, wa.y}, acc);
                acc = v2fma((v2f)(xs[1]), (v2f){wa.z, wa.w}, acc);
                acc = v2fma((v2f)(xs[2]), (v2f){wb.x, wb.y}, acc);
                acc = v2fma((v2f)(xs[3]), (v2f){wb.z, wb.w}, acc);
                v2f th = fast_tanh2_scaled(acc);
                h1[2 * jp]     = th.x;
                h1[2 * jp + 1] = th.y;
            }
            float h2[6];
            #pragma unroll
            for (int jp = 0; jp < 3; ++jp) {
                const float* gb = w + 108 + (k * 3 + jp) * 16;
                float4 w0 = *(const float4*)(gb);       // W2' pairs ww=0,1
                float4 w1 = *(const float4*)(gb + 4);   // W2' pairs ww=2,3
                float4 w2 = *(const float4*)(gb + 8);   // W2' pairs ww=4,5
                v2f acc = *(const v2f*)(gb + 12);       // b2' pair
                acc = v2fma((v2f)(h1[0]), (v2f){w0.x, w0.y}, acc);
                acc = v2fma((v2f)(h1[1]), (v2f){w0.z, w0.w}, acc);
                acc = v2fma((v2f)(h1[2]), (v2f){w1.x, w1.y}, acc);
                acc = v2fma((v2f)(h1[3]), (v2f){w1.z, w1.w}, acc);
                acc = v2fma((v2f)(h1[4]), (v2f){w2.x, w2.y}, acc);
                acc = v2fma((v2f)(h1[5]), (v2f){w2.z, w2.w}, acc);
                v2f th = fast_tanh2_scaled(acc);
                h2[2 * jp]     = th.x;
                h2[2 * jp + 1] = th.y;
            }
            // Layer 3 in the -log2e-scaled domain.
            const float* gc = w + 252 + k * 8;
            float4 c0 = *(const float4*)(gc);   // W3'[0..3]
            v2f c45 = *(const v2f*)(gc + 4);    // W3'[4..5]
            float y = gc[6];                    // b3'
            y = fmaf(h2[0], c0.x, y);
            y = fmaf(h2[1], c0.y, y);
            y = fmaf(h2[2], c0.z, y);
            y = fmaf(h2[3], c0.w, y);
            y = fmaf(h2[4], c45.x, y);
            y = fmaf(h2[5], c45.y, y);
            vals[k] = fmaf(ranges[k], fast_sigmoid_scaled(y), lows[k]);
        }

        float S1max = vals[0], ks = vals[1], nexp = vals[2];
        // (S1/S1max)^n in log2 domain: handles S1==0 (log2->-inf, exp2->0).
        float lr = FAST_LOG2(s1) - FAST_LOG2(S1max);
        float flow = ks * FAST_EXP2(nexp * lr);
        flow = fminf(fmaxf(flow, 0.0f), S1max);
        if (i < n) out[i] = flow;

        if (!has_next) break;
        xv = xv_n;
        s1v = s1_n;
        c = cn;
        i = cn * BLOCK + t;
    }
}

extern "C" void kernel_launch(void* const* d_in, const int* in_sizes, int n_in,
                              void* d_out, int out_size, void* d_ws, size_t ws_size,
                              hipStream_t stream) {
    const float* x  = (const float*)d_in[0];
    const float* S1 = (const float*)d_in[1];
    const float* W1 = (const float*)d_in[2];
    const float* b1 = (const float*)d_in[3];
    const float* W2 = (const float*)d_in[4];
    const float* b2 = (const float*)d_in[5];
    const float* W3 = (const float*)d_in[6];
    const float* b3 = (const float*)d_in[7];
    float* out = (float*)d_out;

    int n = out_size;  // N = 2,000,000 rows, one output per row
    int chunks = (n + BLOCK - 1) / BLOCK;
    int grid = chunks < 2048 ? chunks : 2048;  // 8 blocks/CU x 256 CUs, persistent
    subsurf_kernel<<<grid, BLOCK, 0, stream>>>(x, S1, W1, b1, W2, b2, W3, b3, out, n);
}

// Round 9
// 512.451 us; speedup vs baseline: 1.0157x; 1.0157x over previous
//
#include <hip/hip_runtime.h>

// Fast HW transcendentals (v_exp_f32 / v_log_f32 / v_rcp_f32), with fallbacks.
#if __has_builtin(__builtin_amdgcn_exp2f)
#define FAST_EXP2(x) __builtin_amdgcn_exp2f(x)
#else
#define FAST_EXP2(x) exp2f(x)
#endif
#if __has_builtin(__builtin_amdgcn_logf)
#define FAST_LOG2(x) __builtin_amdgcn_logf(x)
#else
#define FAST_LOG2(x) log2f(x)
#endif
#if __has_builtin(__builtin_amdgcn_rcpf)
#define FAST_RCP(x) __builtin_amdgcn_rcpf(x)
#else
#define FAST_RCP(x) (1.0f / (x))
#endif

#define LOG2E 1.44269504088896340736f

// Compiler-generated vector math ONLY (rounds 4-6 condemned inline-asm v_pk_*).
typedef float v2f __attribute__((ext_vector_type(2)));

__device__ __forceinline__ v2f v2fma(v2f a, v2f b, v2f c) {
    return __builtin_elementwise_fma(a, b, c);
}

// R14: persistent blocks WITHOUT prefetch.
// R13 post-mortem: persistent+prefetch spilled (VGPR collapsed to 32,
// hbm_bytes 1.34 GB of scratch traffic, 447 us) — but it PROVED residency:
// OccupancyPercent 81% persistent vs 9.4% in the 7813-short-block churn
// regime (R9). R10-R12 neutrality is explained by ~3 waves/CU average
// residency from block churn, not by instruction mix. This round keeps the
// 2048-block persistent grid and deletes the software pipeline: plain
// grid-stride loop, loads at top of each iteration (TLP from 8 resident
// waves/SIMD covers the latency). Live state across the unrolled body is
// back to R12's footprint -> should compile clean at (256,8).
// Compute body is verbatim R12 (absmax 1.22e-4 verified twice).

// tanh on a pair whose input is PRE-SCALED by 2*log2e: tanh = 1 - 2/(exp2(t)+1).
// One shared rcp for the pair.
__device__ __forceinline__ v2f fast_tanh2_scaled(v2f t) {
    v2f e;
    e.x = FAST_EXP2(t.x);
    e.y = FAST_EXP2(t.y);
    v2f d = e + (v2f)(1.0f);
    float rp = FAST_RCP(d.x * d.y);
    v2f r;
    r.x = d.y * rp;
    r.y = d.x * rp;
    return v2fma((v2f)(-2.0f), r, (v2f)(1.0f));
}

// sigmoid whose input is PRE-SCALED by -log2e: 1/(1+exp2(t)).
__device__ __forceinline__ float fast_sigmoid_scaled(float t) {
    return FAST_RCP(1.0f + FAST_EXP2(t));
}

constexpr int BLOCK = 256;

__global__ __launch_bounds__(256, 8) void subsurf_kernel(
    const float* __restrict__ x, const float* __restrict__ S1,
    const float* __restrict__ W1, const float* __restrict__ b1,
    const float* __restrict__ W2, const float* __restrict__ b2,
    const float* __restrict__ W3, const float* __restrict__ b3,
    float* __restrict__ out, int n)
{
    // LDS layout (R12's pre-scaled b128-bundled layout):
    //   A (L1): 9 groups x 12 floats @0:   [8x W1' pairs][2x b1'][2 pad] (48B)
    //   B (L2): 9 groups x 16 floats @108: [12x W2' pairs][2x b2'][2 pad] (64B)
    //   C (L3): 3 groups x  8 floats @252: [6x W3'][b3'][pad] (32B)
    __shared__ __align__(16) float w[280];
    int t = threadIdx.x;

    const float SC_H = 2.0f * LOG2E;   // hidden-layer fold (tanh input scale)
    const float SC_O = -LOG2E;         // output-layer fold (sigmoid input scale)
    if (t < 252) {
        if (t < 108) {
            // A region: g=(k*3+jp), r in [0,12)
            int g = t / 12, r = t % 12;
            int k = g / 3, jp = g % 3;
            float v = 0.0f;
            if (r < 8)       v = SC_H * W1[k * 24 + (r >> 1) * 6 + 2 * jp + (r & 1)];
            else if (r < 10) v = SC_H * b1[k * 6 + 2 * jp + (r - 8)];
            w[t] = v;
        } else {
            // B region: u in [0,144), g=(k*3+jp), r in [0,16)
            int u = t - 108;
            int g = u / 16, r = u % 16;
            int k = g / 3, jp = g % 3;
            float v = 0.0f;
            if (r < 12)      v = SC_H * W2[k * 36 + (r >> 1) * 6 + 2 * jp + (r & 1)];
            else if (r < 14) v = SC_H * b2[k * 6 + 2 * jp + (r - 12)];
            w[t] = v;
        }
    }
    if (t < 24) {
        int k = t / 8, r = t % 8;
        float v = 0.0f;
        if (r < 6)       v = SC_O * W3[k * 6 + r];
        else if (r == 6) v = SC_O * b3[k];
        w[252 + t] = v;
    }
    __syncthreads();

    // Bit-match numpy f32 constant arithmetic for lows / (highs - lows).
    const float lows[3]   = {100.0f, 0.01f, 0.01f};
    const float ranges[3] = {500.0f - 100.0f, 100.0f - 0.01f, 10.0f - 0.01f};

    const int chunks = (n + BLOCK - 1) / BLOCK;
    for (int c = blockIdx.x; c < chunks; c += gridDim.x) {
        int i = c * BLOCK + t;
        int ic = min(i, n - 1);   // clamp: always-in-bounds load; store guarded
        float4 xv = ((const float4*)x)[ic];
        float s1 = S1[ic];
        float xs[4] = {xv.x, xv.y, xv.z, xv.w};

        float vals[3];
        #pragma unroll
        for (int k = 0; k < 3; ++k) {
            float h1[6];
            #pragma unroll
            for (int jp = 0; jp < 3; ++jp) {
                const float* ga = w + (k * 3 + jp) * 12;
                float4 wa = *(const float4*)(ga);      // W1' pairs d=0,1
                float4 wb = *(const float4*)(ga + 4);  // W1' pairs d=2,3
                v2f acc = *(const v2f*)(ga + 8);       // b1' pair
                acc = v2fma((v2f)(xs[0]), (v2f){wa.x, wa.y}, acc);
                acc = v2fma((v2f)(xs[1]), (v2f){wa.z, wa.w}, acc);
                acc = v2fma((v2f)(xs[2]), (v2f){wb.x, wb.y}, acc);
                acc = v2fma((v2f)(xs[3]), (v2f){wb.z, wb.w}, acc);
                v2f th = fast_tanh2_scaled(acc);
                h1[2 * jp]     = th.x;
                h1[2 * jp + 1] = th.y;
            }
            float h2[6];
            #pragma unroll
            for (int jp = 0; jp < 3; ++jp) {
                const float* gb = w + 108 + (k * 3 + jp) * 16;
                float4 w0 = *(const float4*)(gb);       // W2' pairs ww=0,1
                float4 w1 = *(const float4*)(gb + 4);   // W2' pairs ww=2,3
                float4 w2 = *(const float4*)(gb + 8);   // W2' pairs ww=4,5
                v2f acc = *(const v2f*)(gb + 12);       // b2' pair
                acc = v2fma((v2f)(h1[0]), (v2f){w0.x, w0.y}, acc);
                acc = v2fma((v2f)(h1[1]), (v2f){w0.z, w0.w}, acc);
                acc = v2fma((v2f)(h1[2]), (v2f){w1.x, w1.y}, acc);
                acc = v2fma((v2f)(h1[3]), (v2f){w1.z, w1.w}, acc);
                acc = v2fma((v2f)(h1[4]), (v2f){w2.x, w2.y}, acc);
                acc = v2fma((v2f)(h1[5]), (v2f){w2.z, w2.w}, acc);
                v2f th = fast_tanh2_scaled(acc);
                h2[2 * jp]     = th.x;
                h2[2 * jp + 1] = th.y;
            }
            // Layer 3 in the -log2e-scaled domain.
            const float* gc = w + 252 + k * 8;
            float4 c0 = *(const float4*)(gc);   // W3'[0..3]
            v2f c45 = *(const v2f*)(gc + 4);    // W3'[4..5]
            float y = gc[6];                    // b3'
            y = fmaf(h2[0], c0.x, y);
            y = fmaf(h2[1], c0.y, y);
            y = fmaf(h2[2], c0.z, y);
            y = fmaf(h2[3], c0.w, y);
            y = fmaf(h2[4], c45.x, y);
            y = fmaf(h2[5], c45.y, y);
            vals[k] = fmaf(ranges[k], fast_sigmoid_scaled(y), lows[k]);
        }

        float S1max = vals[0], ks = vals[1], nexp = vals[2];
        // (S1/S1max)^n in log2 domain: handles S1==0 (log2->-inf, exp2->0).
        float lr = FAST_LOG2(s1) - FAST_LOG2(S1max);
        float flow = ks * FAST_EXP2(nexp * lr);
        flow = fminf(fmaxf(flow, 0.0f), S1max);
        if (i < n) out[i] = flow;
    }
}

extern "C" void kernel_launch(void* const* d_in, const int* in_sizes, int n_in,
                              void* d_out, int out_size, void* d_ws, size_t ws_size,
                              hipStream_t stream) {
    const float* x  = (const float*)d_in[0];
    const float* S1 = (const float*)d_in[1];
    const float* W1 = (const float*)d_in[2];
    const float* b1 = (const float*)d_in[3];
    const float* W2 = (const float*)d_in[4];
    const float* b2 = (const float*)d_in[5];
    const float* W3 = (const float*)d_in[6];
    const float* b3 = (const float*)d_in[7];
    float* out = (float*)d_out;

    int n = out_size;  // N = 2,000,000 rows, one output per row
    int chunks = (n + BLOCK - 1) / BLOCK;
    int grid = chunks < 2048 ? chunks : 2048;  // 8 blocks/CU x 256 CUs, persistent
    subsurf_kernel<<<grid, BLOCK, 0, stream>>>(x, S1, W1, b1, W2, b2, W3, b3, out, n);
}